// Round 1
// baseline (615.923 us; speedup 1.0000x reference)
//
#include <hip/hip_runtime.h>
#include <hip/hip_bf16.h>
#include <stdint.h>

// Problem constants (fixed by the reference)
#define NN    20000      // nodes
#define EE    320000     // edges (w/o self loops)
#define CH    128        // feature width per gate
#define GC    512        // 4 gates * 128
#define NHtot 2560000    // N*CH

// ---------- bf16 helpers ----------
__device__ __forceinline__ float bf2f(unsigned short u) {
    union { unsigned int i; float f; } c; c.i = ((unsigned int)u) << 16; return c.f;
}
__device__ __forceinline__ unsigned short f2bf(float f) {
    __hip_bfloat16 b = __float2bfloat16(f);           // RNE
    union { __hip_bfloat16 b; unsigned short u; } c; c.b = b; return c.u;
}
__device__ __forceinline__ void unpack8(uint4 v, float* f) {
    f[0] = bf2f((unsigned short)(v.x & 0xffff)); f[1] = bf2f((unsigned short)(v.x >> 16));
    f[2] = bf2f((unsigned short)(v.y & 0xffff)); f[3] = bf2f((unsigned short)(v.y >> 16));
    f[4] = bf2f((unsigned short)(v.z & 0xffff)); f[5] = bf2f((unsigned short)(v.z >> 16));
    f[6] = bf2f((unsigned short)(v.w & 0xffff)); f[7] = bf2f((unsigned short)(v.w >> 16));
}
__device__ __forceinline__ uint4 pack8(const float* f) {
    uint4 v;
    v.x = (unsigned int)f2bf(f[0]) | ((unsigned int)f2bf(f[1]) << 16);
    v.y = (unsigned int)f2bf(f[2]) | ((unsigned int)f2bf(f[3]) << 16);
    v.z = (unsigned int)f2bf(f[4]) | ((unsigned int)f2bf(f[5]) << 16);
    v.w = (unsigned int)f2bf(f[6]) | ((unsigned int)f2bf(f[7]) << 16);
    return v;
}

// ---------- 1. degree + in-edge count (atomics over E) ----------
__global__ void k_count(const int* __restrict__ ei, const float* __restrict__ ew,
                        float* __restrict__ deg, int* __restrict__ cnt) {
    int e = blockIdx.x * 256 + threadIdx.x;
    if (e >= EE) return;
    int d = ei[EE + e];                 // dst row
    atomicAdd(&deg[d], ew[e]);
    atomicAdd(&cnt[d], 1);
}

// ---------- 2. dis = rsqrt(deg + 1)  (self loop weight 1; deg>=1 always) ----------
__global__ void k_dis(float* __restrict__ deg) {
    int i = blockIdx.x * 256 + threadIdx.x;
    if (i >= NN) return;
    float dv = deg[i] + 1.0f;
    deg[i] = rsqrtf(fmaxf(dv, 1e-12f));   // in-place: buffer becomes `dis`
}

// ---------- 3. exclusive prefix scan of counts (single wave, 313 chunks) ----------
__global__ void k_scan(const int* __restrict__ cnt, int* __restrict__ rowoff,
                       int* __restrict__ cur) {
    int lane = threadIdx.x;             // 64 threads
    int base = 0;
    for (int start = 0; start < NN; start += 64) {
        int i = start + lane;
        int self = (i < NN) ? cnt[i] : 0;
        int v = self;
        #pragma unroll
        for (int off = 1; off < 64; off <<= 1) {
            int u = __shfl_up(v, off);
            if (lane >= off) v += u;
        }
        if (i < NN) { int ex = base + v - self; rowoff[i] = ex; cur[i] = ex; }
        base += __shfl(v, 63);
    }
    if (lane == 0) rowoff[NN] = base;   // == EE
}

// ---------- 4. scatter edges into CSR with precomputed sym-norm weight ----------
__global__ void k_scatter(const int* __restrict__ ei, const float* __restrict__ ew,
                          const float* __restrict__ dis, int* __restrict__ cur,
                          int* __restrict__ csrs, float* __restrict__ csrn) {
    int e = blockIdx.x * 256 + threadIdx.x;
    if (e >= EE) return;
    int s = ei[e], d = ei[EE + e];
    float nrm = dis[s] * ew[e] * dis[d];
    int p = atomicAdd(&cur[d], 1);
    csrs[p] = s; csrn[p] = nrm;
}

// ---------- 5. prop over 128-wide fp32 features: one wave per dst node ----------
__global__ __launch_bounds__(256) void k_prop128(
        const float* __restrict__ t, float* __restrict__ o,
        const int* __restrict__ rowoff, const int* __restrict__ csrs,
        const float* __restrict__ csrn, const float* __restrict__ dis) {
    int w = (blockIdx.x * 256 + threadIdx.x) >> 6;   // node
    int lane = threadIdx.x & 63;
    if (w >= NN) return;
    float dv = dis[w];
    float sw = dv * dv;                              // self-loop norm
    float a0 = sw * t[(size_t)w * CH + lane];
    float a1 = sw * t[(size_t)w * CH + 64 + lane];
    int e1 = rowoff[w + 1];
    for (int e = rowoff[w]; e < e1; ++e) {
        int   s  = csrs[e];
        float nw = csrn[e];
        a0 += nw * t[(size_t)s * CH + lane];
        a1 += nw * t[(size_t)s * CH + 64 + lane];
    }
    o[(size_t)w * CH + lane]      = a0;
    o[(size_t)w * CH + 64 + lane] = a1;
}

// ---------- 6. GEMM1: h0 = relu(A[N,128] @ W0[g] + b0[g]) -> bf16 [N,512] ----------
// block: 32 rows x 128 cols (one gate). LDS: A fp32 (padded), W bf16. ~49 KB -> 3 blk/CU.
__global__ __launch_bounds__(256) void k_gemm1(
        const float* __restrict__ A, const float* __restrict__ W,
        const float* __restrict__ bias, __hip_bfloat16* __restrict__ out) {
    __shared__ float          As[32][132];
    __shared__ unsigned short Bs[128][128];
    const int g    = blockIdx.y;
    const int row0 = blockIdx.x * 32;                // N % 32 == 0
    const int t    = threadIdx.x;

    #pragma unroll
    for (int p = 0; p < 4; ++p) {                    // stage A: 32x128 fp32
        int id = t + 256 * p;                        // 0..1023 float4s
        int r = id >> 5, c4 = id & 31;
        float4 v = *(const float4*)(A + (size_t)(row0 + r) * CH + c4 * 4);
        *(float4*)&As[r][c4 * 4] = v;
    }
    const float* Wg = W + (size_t)g * CH * CH;       // W0[g][c][h]
    #pragma unroll
    for (int p = 0; p < 16; ++p) {                   // stage W -> bf16
        int id = t + 256 * p;                        // 0..4095 float4s
        int k = id >> 5, c4 = id & 31;
        float4 v = *(const float4*)(Wg + k * CH + c4 * 4);
        Bs[k][c4 * 4 + 0] = f2bf(v.x);
        Bs[k][c4 * 4 + 1] = f2bf(v.y);
        Bs[k][c4 * 4 + 2] = f2bf(v.z);
        Bs[k][c4 * 4 + 3] = f2bf(v.w);
    }
    __syncthreads();

    const int tx = t & 31, ty = t >> 5;              // 4 cols x 4 rows per thread
    float acc[4][4] = {};
    #pragma unroll 8
    for (int k = 0; k < 128; ++k) {
        float a0 = As[ty * 4 + 0][k], a1 = As[ty * 4 + 1][k];
        float a2 = As[ty * 4 + 2][k], a3 = As[ty * 4 + 3][k];
        ushort4 bu = *(const ushort4*)&Bs[k][tx * 4];
        float b0 = bf2f(bu.x), b1 = bf2f(bu.y), b2 = bf2f(bu.z), b3 = bf2f(bu.w);
        acc[0][0] += a0 * b0; acc[0][1] += a0 * b1; acc[0][2] += a0 * b2; acc[0][3] += a0 * b3;
        acc[1][0] += a1 * b0; acc[1][1] += a1 * b1; acc[1][2] += a1 * b2; acc[1][3] += a1 * b3;
        acc[2][0] += a2 * b0; acc[2][1] += a2 * b1; acc[2][2] += a2 * b2; acc[2][3] += a2 * b3;
        acc[3][0] += a3 * b0; acc[3][1] += a3 * b1; acc[3][2] += a3 * b2; acc[3][3] += a3 * b3;
    }
    float bb0 = bias[g * CH + tx * 4 + 0], bb1 = bias[g * CH + tx * 4 + 1];
    float bb2 = bias[g * CH + tx * 4 + 2], bb3 = bias[g * CH + tx * 4 + 3];
    unsigned short* op = (unsigned short*)out;
    #pragma unroll
    for (int i = 0; i < 4; ++i) {
        int n = row0 + ty * 4 + i;
        ushort4 o;
        o.x = f2bf(fmaxf(acc[i][0] + bb0, 0.f));
        o.y = f2bf(fmaxf(acc[i][1] + bb1, 0.f));
        o.z = f2bf(fmaxf(acc[i][2] + bb2, 0.f));
        o.w = f2bf(fmaxf(acc[i][3] + bb3, 0.f));
        *(ushort4*)(op + (size_t)n * GC + g * CH + tx * 4) = o;
    }
}

// ---------- 7. GEMM2 (fused both sides): S[g] = h0x[g]@Wx1[g] + h0h[g]@Wh1[g] ----------
// Two sequential passes reusing the same LDS buffers (~41 KB -> 3 blk/CU). No bias.
__global__ __launch_bounds__(256) void k_gemm2(
        const __hip_bfloat16* __restrict__ A1, const __hip_bfloat16* __restrict__ A2,
        const float* __restrict__ W1, const float* __restrict__ W2,
        __hip_bfloat16* __restrict__ outS) {
    __shared__ unsigned short As[32][132];
    __shared__ unsigned short Bs[128][128];
    const int g    = blockIdx.y;
    const int row0 = blockIdx.x * 32;
    const int t    = threadIdx.x;
    const int tx   = t & 31, ty = t >> 5;
    float acc[4][4] = {};

    const unsigned short* Aarr[2] = { (const unsigned short*)A1, (const unsigned short*)A2 };
    const float*          Warr[2] = { W1, W2 };

    for (int side = 0; side < 2; ++side) {
        const unsigned short* Ap = Aarr[side];
        #pragma unroll
        for (int p = 0; p < 4; ++p) {                // stage A tile (bf16)
            int id = t + 256 * p;                    // 0..1023 ushort4s
            int r = id >> 5, c4 = id & 31;
            ushort4 v = *(const ushort4*)(Ap + (size_t)(row0 + r) * GC + g * CH + c4 * 4);
            *(ushort4*)&As[r][c4 * 4] = v;
        }
        const float* Wg = Warr[side] + (size_t)g * CH * CH;  // W1[g][h][k]
        #pragma unroll
        for (int p = 0; p < 16; ++p) {               // stage W -> bf16
            int id = t + 256 * p;
            int k = id >> 5, c4 = id & 31;
            float4 v = *(const float4*)(Wg + k * CH + c4 * 4);
            Bs[k][c4 * 4 + 0] = f2bf(v.x);
            Bs[k][c4 * 4 + 1] = f2bf(v.y);
            Bs[k][c4 * 4 + 2] = f2bf(v.z);
            Bs[k][c4 * 4 + 3] = f2bf(v.w);
        }
        __syncthreads();
        #pragma unroll 8
        for (int k = 0; k < 128; ++k) {
            float a0 = bf2f(As[ty * 4 + 0][k]), a1 = bf2f(As[ty * 4 + 1][k]);
            float a2 = bf2f(As[ty * 4 + 2][k]), a3 = bf2f(As[ty * 4 + 3][k]);
            ushort4 bu = *(const ushort4*)&Bs[k][tx * 4];
            float b0 = bf2f(bu.x), b1 = bf2f(bu.y), b2 = bf2f(bu.z), b3 = bf2f(bu.w);
            acc[0][0] += a0 * b0; acc[0][1] += a0 * b1; acc[0][2] += a0 * b2; acc[0][3] += a0 * b3;
            acc[1][0] += a1 * b0; acc[1][1] += a1 * b1; acc[1][2] += a1 * b2; acc[1][3] += a1 * b3;
            acc[2][0] += a2 * b0; acc[2][1] += a2 * b1; acc[2][2] += a2 * b2; acc[2][3] += a2 * b3;
            acc[3][0] += a3 * b0; acc[3][1] += a3 * b1; acc[3][2] += a3 * b2; acc[3][3] += a3 * b3;
        }
        __syncthreads();                             // before re-staging
    }
    unsigned short* op = (unsigned short*)outS;
    #pragma unroll
    for (int i = 0; i < 4; ++i) {
        int n = row0 + ty * 4 + i;
        ushort4 o;
        o.x = f2bf(acc[i][0]); o.y = f2bf(acc[i][1]);
        o.z = f2bf(acc[i][2]); o.w = f2bf(acc[i][3]);
        *(ushort4*)(op + (size_t)n * GC + g * CH + tx * 4) = o;
    }
}

// ---------- 8. prop over 512-wide bf16: one wave per node, 16B/lane gathers ----------
__global__ __launch_bounds__(256) void k_prop512(
        const __hip_bfloat16* __restrict__ Sb, __hip_bfloat16* __restrict__ G0,
        const int* __restrict__ rowoff, const int* __restrict__ csrs,
        const float* __restrict__ csrn, const float* __restrict__ dis) {
    int w = (blockIdx.x * 256 + threadIdx.x) >> 6;
    int lane = threadIdx.x & 63;
    if (w >= NN) return;
    const uint4* S4 = (const uint4*)Sb;              // 8 bf16 per lane
    float dv = dis[w], sw = dv * dv;
    float acc[8], vals[8];
    uint4 v = S4[(size_t)w * 64 + lane];
    unpack8(v, vals);
    #pragma unroll
    for (int j = 0; j < 8; ++j) acc[j] = sw * vals[j];
    int e1 = rowoff[w + 1];
    for (int e = rowoff[w]; e < e1; ++e) {
        int   s  = csrs[e];
        float nw = csrn[e];
        v = S4[(size_t)s * 64 + lane];
        unpack8(v, vals);
        #pragma unroll
        for (int j = 0; j < 8; ++j) acc[j] += nw * vals[j];
    }
    ((uint4*)G0)[(size_t)w * 64 + lane] = pack8(acc);
}

// ---------- 9. LSTM gate elementwise ----------
__global__ void k_gates(const __hip_bfloat16* __restrict__ G0, const float* __restrict__ c,
                        const float* __restrict__ bx1, const float* __restrict__ bh1,
                        const float* __restrict__ wc, const float* __restrict__ bg,
                        float* __restrict__ out) {
    int idx = blockIdx.x * 256 + threadIdx.x;        // < NHtot (exact grid)
    int n = idx >> 7, hh = idx & 127;
    const unsigned short* G = (const unsigned short*)G0;
    size_t base = (size_t)n * GC + hh;
    float g0 = bf2f(G[base])       + bx1[hh]       + bh1[hh];
    float g1 = bf2f(G[base + 128]) + bx1[128 + hh] + bh1[128 + hh];
    float g2 = bf2f(G[base + 256]) + bx1[256 + hh] + bh1[256 + hh];
    float g3 = bf2f(G[base + 384]) + bx1[384 + hh] + bh1[384 + hh];
    float cv = c[idx];
    float I  = 1.f / (1.f + expf(-(g0 + wc[hh]       * cv + bg[hh])));
    float F  = 1.f / (1.f + expf(-(g1 + wc[128 + hh] * cv + bg[128 + hh])));
    float T  = tanhf(g2 + bg[256 + hh]);
    float Cn = F * cv + I * T;
    float O  = 1.f / (1.f + expf(-(g3 + wc[256 + hh] * Cn + bg[384 + hh])));
    out[idx]         = O * tanhf(Cn);                // Hn
    out[NHtot + idx] = Cn;                           // Cn
}

extern "C" void kernel_launch(void* const* d_in, const int* in_sizes, int n_in,
                              void* d_out, int out_size, void* d_ws, size_t ws_size,
                              hipStream_t stream) {
    (void)in_sizes; (void)n_in; (void)out_size; (void)ws_size;
    const float* x   = (const float*)d_in[0];
    const int*   ei  = (const int*)d_in[1];
    const float* ew  = (const float*)d_in[2];
    const float* h   = (const float*)d_in[3];
    const float* c   = (const float*)d_in[4];
    const float* Wx0 = (const float*)d_in[5];
    const float* bx0 = (const float*)d_in[6];
    const float* Wx1 = (const float*)d_in[7];
    const float* bx1 = (const float*)d_in[8];
    const float* Wh0 = (const float*)d_in[9];
    const float* bh0 = (const float*)d_in[10];
    const float* Wh1 = (const float*)d_in[11];
    const float* bh1 = (const float*)d_in[12];
    const float* wc  = (const float*)d_in[13];
    const float* bg  = (const float*)d_in[14];
    float* out = (float*)d_out;

    // Workspace layout (float units). Total ~85 MB.
    float* wsf  = (float*)d_ws;
    float* deg  = wsf;                        // [20480] -> becomes dis
    int*   cnt  = (int*)(wsf + 20480);        // [20480]
    int*   row  = (int*)(wsf + 40960);        // [N+1]
    int*   cur  = (int*)(wsf + 61696);        // [20480]
    int*   csrs = (int*)(wsf + 82176);        // [E]
    float* csrn = wsf + 402176;               // [E]
    float* ax   = wsf + 722176;               // [N*128] fp32
    float* ah   = wsf + 3282176;              // [N*128] fp32
    __hip_bfloat16* h0x = (__hip_bfloat16*)(wsf + 5842176);  // [N*512] bf16
    __hip_bfloat16* h0h = h0x + 10240000;
    __hip_bfloat16* Sb  = h0h + 10240000;
    __hip_bfloat16* G0  = h0x;                // alias: h0x dead after GEMM2

    hipMemsetAsync(deg, 0, 2 * 20480 * sizeof(float), stream);  // deg + cnt

    k_count  <<<EE / 256, 256, 0, stream>>>(ei, ew, deg, cnt);
    k_dis    <<<(NN + 255) / 256, 256, 0, stream>>>(deg);
    k_scan   <<<1, 64, 0, stream>>>(cnt, row, cur);
    k_scatter<<<EE / 256, 256, 0, stream>>>(ei, ew, deg, cur, csrs, csrn);

    k_prop128<<<NN / 4, 256, 0, stream>>>(x, ax, row, csrs, csrn, deg);
    k_prop128<<<NN / 4, 256, 0, stream>>>(h, ah, row, csrs, csrn, deg);

    dim3 gg(NN / 32, 4);
    k_gemm1<<<gg, 256, 0, stream>>>(ax, Wx0, bx0, h0x);
    k_gemm1<<<gg, 256, 0, stream>>>(ah, Wh0, bh0, h0h);
    k_gemm2<<<gg, 256, 0, stream>>>(h0x, h0h, Wx1, Wh1, Sb);

    k_prop512<<<NN / 4, 256, 0, stream>>>(Sb, G0, row, csrs, csrn, deg);
    k_gates  <<<NHtot / 256, 256, 0, stream>>>(G0, c, bx1, bh1, wc, bg, out);
}

// Round 2
// 464.459 us; speedup vs baseline: 1.3261x; 1.3261x over previous
//
#include <hip/hip_runtime.h>
#include <hip/hip_bf16.h>
#include <stdint.h>

// Problem constants (fixed by the reference)
#define NN    20000      // nodes
#define EE    320000     // edges (w/o self loops)
#define CH    128        // feature width per gate
#define GC    512        // 4 gates * 128
#define NHtot 2560000    // N*CH

// ---------- bf16 helpers ----------
__device__ __forceinline__ float bf2f(unsigned short u) {
    union { unsigned int i; float f; } c; c.i = ((unsigned int)u) << 16; return c.f;
}
__device__ __forceinline__ unsigned short f2bf(float f) {
    __hip_bfloat16 b = __float2bfloat16(f);           // RNE
    union { __hip_bfloat16 b; unsigned short u; } c; c.b = b; return c.u;
}
__device__ __forceinline__ void unpack8(uint4 v, float* f) {
    f[0] = bf2f((unsigned short)(v.x & 0xffff)); f[1] = bf2f((unsigned short)(v.x >> 16));
    f[2] = bf2f((unsigned short)(v.y & 0xffff)); f[3] = bf2f((unsigned short)(v.y >> 16));
    f[4] = bf2f((unsigned short)(v.z & 0xffff)); f[5] = bf2f((unsigned short)(v.z >> 16));
    f[6] = bf2f((unsigned short)(v.w & 0xffff)); f[7] = bf2f((unsigned short)(v.w >> 16));
}
__device__ __forceinline__ uint4 pack8(const float* f) {
    uint4 v;
    v.x = (unsigned int)f2bf(f[0]) | ((unsigned int)f2bf(f[1]) << 16);
    v.y = (unsigned int)f2bf(f[2]) | ((unsigned int)f2bf(f[3]) << 16);
    v.z = (unsigned int)f2bf(f[4]) | ((unsigned int)f2bf(f[5]) << 16);
    v.w = (unsigned int)f2bf(f[6]) | ((unsigned int)f2bf(f[7]) << 16);
    return v;
}

// ---------- 1. degree + in-edge count (atomics over E) ----------
__global__ void k_count(const int* __restrict__ ei, const float* __restrict__ ew,
                        float* __restrict__ deg, int* __restrict__ cnt) {
    int e = blockIdx.x * 256 + threadIdx.x;
    if (e >= EE) return;
    int d = ei[EE + e];                 // dst row
    atomicAdd(&deg[d], ew[e]);
    atomicAdd(&cnt[d], 1);
}

// ---------- 2. dis = rsqrt(deg + 1)  (self loop weight 1; deg>=1 always) ----------
__global__ void k_dis(float* __restrict__ deg) {
    int i = blockIdx.x * 256 + threadIdx.x;
    if (i >= NN) return;
    float dv = deg[i] + 1.0f;
    deg[i] = rsqrtf(fmaxf(dv, 1e-12f));   // in-place: buffer becomes `dis`
}

// ---------- 3. hierarchical exclusive scan of counts (3 kernels, ~6 us total) ----------
// scan1: per-block (256) exclusive prescan into rowoff, block totals into bsum[80]
__global__ void k_scan1(const int* __restrict__ cnt, int* __restrict__ rowoff,
                        int* __restrict__ bsum) {
    __shared__ int wsum[4];
    int i = blockIdx.x * 256 + threadIdx.x;
    int self = (i < NN) ? cnt[i] : 0;
    int lane = threadIdx.x & 63, wid = threadIdx.x >> 6;
    int v = self;
    #pragma unroll
    for (int off = 1; off < 64; off <<= 1) {
        int u = __shfl_up(v, off);
        if (lane >= off) v += u;
    }
    if (lane == 63) wsum[wid] = v;
    __syncthreads();
    int wof = 0;
    for (int k = 0; k < wid; ++k) wof += wsum[k];
    if (i < NN) rowoff[i] = wof + v - self;          // block-local exclusive
    if (threadIdx.x == 255) bsum[blockIdx.x] = wof + v;  // block total
}

// scan2: single wave scans the 80 block sums in place (exclusive)
__global__ void k_scan2(int* __restrict__ bsum) {
    int lane = threadIdx.x;                          // 64 threads
    int base = 0;
    for (int start = 0; start < 80; start += 64) {
        int i = start + lane;
        int self = (i < 80) ? bsum[i] : 0;
        int v = self;
        #pragma unroll
        for (int off = 1; off < 64; off <<= 1) {
            int u = __shfl_up(v, off);
            if (lane >= off) v += u;
        }
        if (i < 80) bsum[i] = base + v - self;
        base += __shfl(v, 63);
    }
}

// scan3: add block offset in place; mirror into cur; rowoff[NN] = EE
__global__ void k_scan3(int* __restrict__ rowoff, const int* __restrict__ bsum,
                        int* __restrict__ cur) {
    int i = blockIdx.x * 256 + threadIdx.x;
    if (i < NN) {
        int v = rowoff[i] + bsum[i >> 8];
        rowoff[i] = v; cur[i] = v;
    }
    if (i == NN) rowoff[NN] = EE;                    // total weight-count is exactly E
}

// ---------- 4. scatter edges into CSR with precomputed sym-norm weight ----------
__global__ void k_scatter(const int* __restrict__ ei, const float* __restrict__ ew,
                          const float* __restrict__ dis, int* __restrict__ cur,
                          int* __restrict__ csrs, float* __restrict__ csrn) {
    int e = blockIdx.x * 256 + threadIdx.x;
    if (e >= EE) return;
    int s = ei[e], d = ei[EE + e];
    float nrm = dis[s] * ew[e] * dis[d];
    int p = atomicAdd(&cur[d], 1);
    csrs[p] = s; csrn[p] = nrm;
}

// ---------- 5. prop over 128-wide fp32 features: one wave per dst node ----------
__global__ __launch_bounds__(256) void k_prop128(
        const float* __restrict__ t, float* __restrict__ o,
        const int* __restrict__ rowoff, const int* __restrict__ csrs,
        const float* __restrict__ csrn, const float* __restrict__ dis) {
    int w = (blockIdx.x * 256 + threadIdx.x) >> 6;   // node
    int lane = threadIdx.x & 63;
    if (w >= NN) return;
    float dv = dis[w];
    float sw = dv * dv;                              // self-loop norm
    float a0 = sw * t[(size_t)w * CH + lane];
    float a1 = sw * t[(size_t)w * CH + 64 + lane];
    int e1 = rowoff[w + 1];
    for (int e = rowoff[w]; e < e1; ++e) {
        int   s  = csrs[e];
        float nw = csrn[e];
        a0 += nw * t[(size_t)s * CH + lane];
        a1 += nw * t[(size_t)s * CH + 64 + lane];
    }
    o[(size_t)w * CH + lane]      = a0;
    o[(size_t)w * CH + 64 + lane] = a1;
}

// ---------- 6. GEMM1: h0 = relu(A[N,128] @ W0[g] + b0[g]) -> bf16 [N,512] ----------
__global__ __launch_bounds__(256) void k_gemm1(
        const float* __restrict__ A, const float* __restrict__ W,
        const float* __restrict__ bias, __hip_bfloat16* __restrict__ out) {
    __shared__ float          As[32][132];
    __shared__ unsigned short Bs[128][128];
    const int g    = blockIdx.y;
    const int row0 = blockIdx.x * 32;                // N % 32 == 0
    const int t    = threadIdx.x;

    #pragma unroll
    for (int p = 0; p < 4; ++p) {                    // stage A: 32x128 fp32
        int id = t + 256 * p;                        // 0..1023 float4s
        int r = id >> 5, c4 = id & 31;
        float4 v = *(const float4*)(A + (size_t)(row0 + r) * CH + c4 * 4);
        *(float4*)&As[r][c4 * 4] = v;
    }
    const float* Wg = W + (size_t)g * CH * CH;       // W0[g][c][h]
    #pragma unroll
    for (int p = 0; p < 16; ++p) {                   // stage W -> bf16
        int id = t + 256 * p;                        // 0..4095 float4s
        int k = id >> 5, c4 = id & 31;
        float4 v = *(const float4*)(Wg + k * CH + c4 * 4);
        Bs[k][c4 * 4 + 0] = f2bf(v.x);
        Bs[k][c4 * 4 + 1] = f2bf(v.y);
        Bs[k][c4 * 4 + 2] = f2bf(v.z);
        Bs[k][c4 * 4 + 3] = f2bf(v.w);
    }
    __syncthreads();

    const int tx = t & 31, ty = t >> 5;              // 4 cols x 4 rows per thread
    float acc[4][4] = {};
    #pragma unroll 8
    for (int k = 0; k < 128; ++k) {
        float a0 = As[ty * 4 + 0][k], a1 = As[ty * 4 + 1][k];
        float a2 = As[ty * 4 + 2][k], a3 = As[ty * 4 + 3][k];
        ushort4 bu = *(const ushort4*)&Bs[k][tx * 4];
        float b0 = bf2f(bu.x), b1 = bf2f(bu.y), b2 = bf2f(bu.z), b3 = bf2f(bu.w);
        acc[0][0] += a0 * b0; acc[0][1] += a0 * b1; acc[0][2] += a0 * b2; acc[0][3] += a0 * b3;
        acc[1][0] += a1 * b0; acc[1][1] += a1 * b1; acc[1][2] += a1 * b2; acc[1][3] += a1 * b3;
        acc[2][0] += a2 * b0; acc[2][1] += a2 * b1; acc[2][2] += a2 * b2; acc[2][3] += a2 * b3;
        acc[3][0] += a3 * b0; acc[3][1] += a3 * b1; acc[3][2] += a3 * b2; acc[3][3] += a3 * b3;
    }
    float bb0 = bias[g * CH + tx * 4 + 0], bb1 = bias[g * CH + tx * 4 + 1];
    float bb2 = bias[g * CH + tx * 4 + 2], bb3 = bias[g * CH + tx * 4 + 3];
    unsigned short* op = (unsigned short*)out;
    #pragma unroll
    for (int i = 0; i < 4; ++i) {
        int n = row0 + ty * 4 + i;
        ushort4 o;
        o.x = f2bf(fmaxf(acc[i][0] + bb0, 0.f));
        o.y = f2bf(fmaxf(acc[i][1] + bb1, 0.f));
        o.z = f2bf(fmaxf(acc[i][2] + bb2, 0.f));
        o.w = f2bf(fmaxf(acc[i][3] + bb3, 0.f));
        *(ushort4*)(op + (size_t)n * GC + g * CH + tx * 4) = o;
    }
}

// ---------- 7. GEMM2 (fused both sides): S[g] = h0x[g]@Wx1[g] + h0h[g]@Wh1[g] ----------
__global__ __launch_bounds__(256) void k_gemm2(
        const __hip_bfloat16* __restrict__ A1, const __hip_bfloat16* __restrict__ A2,
        const float* __restrict__ W1, const float* __restrict__ W2,
        __hip_bfloat16* __restrict__ outS) {
    __shared__ unsigned short As[32][132];
    __shared__ unsigned short Bs[128][128];
    const int g    = blockIdx.y;
    const int row0 = blockIdx.x * 32;
    const int t    = threadIdx.x;
    const int tx   = t & 31, ty = t >> 5;
    float acc[4][4] = {};

    const unsigned short* Aarr[2] = { (const unsigned short*)A1, (const unsigned short*)A2 };
    const float*          Warr[2] = { W1, W2 };

    for (int side = 0; side < 2; ++side) {
        const unsigned short* Ap = Aarr[side];
        #pragma unroll
        for (int p = 0; p < 4; ++p) {                // stage A tile (bf16)
            int id = t + 256 * p;                    // 0..1023 ushort4s
            int r = id >> 5, c4 = id & 31;
            ushort4 v = *(const ushort4*)(Ap + (size_t)(row0 + r) * GC + g * CH + c4 * 4);
            *(ushort4*)&As[r][c4 * 4] = v;
        }
        const float* Wg = Warr[side] + (size_t)g * CH * CH;  // W1[g][h][k]
        #pragma unroll
        for (int p = 0; p < 16; ++p) {               // stage W -> bf16
            int id = t + 256 * p;
            int k = id >> 5, c4 = id & 31;
            float4 v = *(const float4*)(Wg + k * CH + c4 * 4);
            Bs[k][c4 * 4 + 0] = f2bf(v.x);
            Bs[k][c4 * 4 + 1] = f2bf(v.y);
            Bs[k][c4 * 4 + 2] = f2bf(v.z);
            Bs[k][c4 * 4 + 3] = f2bf(v.w);
        }
        __syncthreads();
        #pragma unroll 8
        for (int k = 0; k < 128; ++k) {
            float a0 = bf2f(As[ty * 4 + 0][k]), a1 = bf2f(As[ty * 4 + 1][k]);
            float a2 = bf2f(As[ty * 4 + 2][k]), a3 = bf2f(As[ty * 4 + 3][k]);
            ushort4 bu = *(const ushort4*)&Bs[k][tx * 4];
            float b0 = bf2f(bu.x), b1 = bf2f(bu.y), b2 = bf2f(bu.z), b3 = bf2f(bu.w);
            acc[0][0] += a0 * b0; acc[0][1] += a0 * b1; acc[0][2] += a0 * b2; acc[0][3] += a0 * b3;
            acc[1][0] += a1 * b0; acc[1][1] += a1 * b1; acc[1][2] += a1 * b2; acc[1][3] += a1 * b3;
            acc[2][0] += a2 * b0; acc[2][1] += a2 * b1; acc[2][2] += a2 * b2; acc[2][3] += a2 * b3;
            acc[3][0] += a3 * b0; acc[3][1] += a3 * b1; acc[3][2] += a3 * b2; acc[3][3] += a3 * b3;
        }
        __syncthreads();                             // before re-staging
    }
    unsigned short* op = (unsigned short*)outS;
    #pragma unroll
    for (int i = 0; i < 4; ++i) {
        int n = row0 + ty * 4 + i;
        ushort4 o;
        o.x = f2bf(acc[i][0]); o.y = f2bf(acc[i][1]);
        o.z = f2bf(acc[i][2]); o.w = f2bf(acc[i][3]);
        *(ushort4*)(op + (size_t)n * GC + g * CH + tx * 4) = o;
    }
}

// ---------- 8. prop over 512-wide bf16: one wave per node, 16B/lane gathers ----------
__global__ __launch_bounds__(256) void k_prop512(
        const __hip_bfloat16* __restrict__ Sb, __hip_bfloat16* __restrict__ G0,
        const int* __restrict__ rowoff, const int* __restrict__ csrs,
        const float* __restrict__ csrn, const float* __restrict__ dis) {
    int w = (blockIdx.x * 256 + threadIdx.x) >> 6;
    int lane = threadIdx.x & 63;
    if (w >= NN) return;
    const uint4* S4 = (const uint4*)Sb;              // 8 bf16 per lane
    float dv = dis[w], sw = dv * dv;
    float acc[8], vals[8];
    uint4 v = S4[(size_t)w * 64 + lane];
    unpack8(v, vals);
    #pragma unroll
    for (int j = 0; j < 8; ++j) acc[j] = sw * vals[j];
    int e1 = rowoff[w + 1];
    for (int e = rowoff[w]; e < e1; ++e) {
        int   s  = csrs[e];
        float nw = csrn[e];
        v = S4[(size_t)s * 64 + lane];
        unpack8(v, vals);
        #pragma unroll
        for (int j = 0; j < 8; ++j) acc[j] += nw * vals[j];
    }
    ((uint4*)G0)[(size_t)w * 64 + lane] = pack8(acc);
}

// ---------- 9. LSTM gate elementwise ----------
__global__ void k_gates(const __hip_bfloat16* __restrict__ G0, const float* __restrict__ c,
                        const float* __restrict__ bx1, const float* __restrict__ bh1,
                        const float* __restrict__ wc, const float* __restrict__ bg,
                        float* __restrict__ out) {
    int idx = blockIdx.x * 256 + threadIdx.x;        // < NHtot (exact grid)
    int n = idx >> 7, hh = idx & 127;
    const unsigned short* G = (const unsigned short*)G0;
    size_t base = (size_t)n * GC + hh;
    float g0 = bf2f(G[base])       + bx1[hh]       + bh1[hh];
    float g1 = bf2f(G[base + 128]) + bx1[128 + hh] + bh1[128 + hh];
    float g2 = bf2f(G[base + 256]) + bx1[256 + hh] + bh1[256 + hh];
    float g3 = bf2f(G[base + 384]) + bx1[384 + hh] + bh1[384 + hh];
    float cv = c[idx];
    float I  = 1.f / (1.f + expf(-(g0 + wc[hh]       * cv + bg[hh])));
    float F  = 1.f / (1.f + expf(-(g1 + wc[128 + hh] * cv + bg[128 + hh])));
    float T  = tanhf(g2 + bg[256 + hh]);
    float Cn = F * cv + I * T;
    float O  = 1.f / (1.f + expf(-(g3 + wc[256 + hh] * Cn + bg[384 + hh])));
    out[idx]         = O * tanhf(Cn);                // Hn
    out[NHtot + idx] = Cn;                           // Cn
}

extern "C" void kernel_launch(void* const* d_in, const int* in_sizes, int n_in,
                              void* d_out, int out_size, void* d_ws, size_t ws_size,
                              hipStream_t stream) {
    (void)in_sizes; (void)n_in; (void)out_size; (void)ws_size;
    const float* x   = (const float*)d_in[0];
    const int*   ei  = (const int*)d_in[1];
    const float* ew  = (const float*)d_in[2];
    const float* h   = (const float*)d_in[3];
    const float* c   = (const float*)d_in[4];
    const float* Wx0 = (const float*)d_in[5];
    const float* bx0 = (const float*)d_in[6];
    const float* Wx1 = (const float*)d_in[7];
    const float* bx1 = (const float*)d_in[8];
    const float* Wh0 = (const float*)d_in[9];
    const float* bh0 = (const float*)d_in[10];
    const float* Wh1 = (const float*)d_in[11];
    const float* bh1 = (const float*)d_in[12];
    const float* wc  = (const float*)d_in[13];
    const float* bg  = (const float*)d_in[14];
    float* out = (float*)d_out;

    // Workspace layout (float units). Total ~85 MB.
    float* wsf  = (float*)d_ws;
    float* deg  = wsf;                        // [20480] -> becomes dis
    int*   cnt  = (int*)(wsf + 20480);        // [20480]
    int*   row  = (int*)(wsf + 40960);        // [N+1]
    int*   cur  = (int*)(wsf + 61696);        // [20480]
    int*   bsum = (int*)(wsf + 82176);        // [80]
    int*   csrs = (int*)(wsf + 82432);        // [E]
    float* csrn = wsf + 402432;               // [E]
    float* ax   = wsf + 722432;               // [N*128] fp32
    float* ah   = wsf + 3282432;              // [N*128] fp32
    __hip_bfloat16* h0x = (__hip_bfloat16*)(wsf + 5842432);  // [N*512] bf16
    __hip_bfloat16* h0h = h0x + 10240000;
    __hip_bfloat16* Sb  = h0h + 10240000;
    __hip_bfloat16* G0  = h0x;                // alias: h0x dead after GEMM2

    hipMemsetAsync(deg, 0, 2 * 20480 * sizeof(float), stream);  // deg + cnt

    k_count  <<<EE / 256, 256, 0, stream>>>(ei, ew, deg, cnt);
    k_dis    <<<(NN + 255) / 256, 256, 0, stream>>>(deg);
    k_scan1  <<<80, 256, 0, stream>>>(cnt, row, bsum);
    k_scan2  <<<1, 64, 0, stream>>>(bsum);
    k_scan3  <<<80, 256, 0, stream>>>(row, bsum, cur);
    k_scatter<<<EE / 256, 256, 0, stream>>>(ei, ew, deg, cur, csrs, csrn);

    k_prop128<<<NN / 4, 256, 0, stream>>>(x, ax, row, csrs, csrn, deg);
    k_prop128<<<NN / 4, 256, 0, stream>>>(h, ah, row, csrs, csrn, deg);

    dim3 gg(NN / 32, 4);
    k_gemm1<<<gg, 256, 0, stream>>>(ax, Wx0, bx0, h0x);
    k_gemm1<<<gg, 256, 0, stream>>>(ah, Wh0, bh0, h0h);
    k_gemm2<<<gg, 256, 0, stream>>>(h0x, h0h, Wx1, Wh1, Sb);

    k_prop512<<<NN / 4, 256, 0, stream>>>(Sb, G0, row, csrs, csrn, deg);
    k_gates  <<<NHtot / 256, 256, 0, stream>>>(G0, c, bx1, bh1, wc, bg, out);
}

// Round 3
// 339.189 us; speedup vs baseline: 1.8159x; 1.3693x over previous
//
#include <hip/hip_runtime.h>
#include <hip/hip_bf16.h>
#include <stdint.h>

// Problem constants (fixed by the reference)
#define NN    20000      // nodes
#define NP    20096      // nodes padded to 157*128 (garbage rows never read back)
#define EE    320000     // edges (w/o self loops)
#define CH    128        // feature width per gate
#define GC    512        // 4 gates * 128
#define NHtot 2560000    // N*CH

typedef short bf16x8 __attribute__((ext_vector_type(8)));   // 8 bf16 (4 VGPRs)
typedef float f32x4  __attribute__((ext_vector_type(4)));   // 4 fp32 acc

// ---------- bf16 helpers ----------
__device__ __forceinline__ float bf2f(unsigned short u) {
    union { unsigned int i; float f; } c; c.i = ((unsigned int)u) << 16; return c.f;
}
__device__ __forceinline__ unsigned short f2bf(float f) {
    __hip_bfloat16 b = __float2bfloat16(f);           // RNE
    union { __hip_bfloat16 b; unsigned short u; } c; c.b = b; return c.u;
}
__device__ __forceinline__ void unpack8(uint4 v, float* f) {
    f[0] = bf2f((unsigned short)(v.x & 0xffff)); f[1] = bf2f((unsigned short)(v.x >> 16));
    f[2] = bf2f((unsigned short)(v.y & 0xffff)); f[3] = bf2f((unsigned short)(v.y >> 16));
    f[4] = bf2f((unsigned short)(v.z & 0xffff)); f[5] = bf2f((unsigned short)(v.z >> 16));
    f[6] = bf2f((unsigned short)(v.w & 0xffff)); f[7] = bf2f((unsigned short)(v.w >> 16));
}
__device__ __forceinline__ uint4 pack8(const float* f) {
    uint4 v;
    v.x = (unsigned int)f2bf(f[0]) | ((unsigned int)f2bf(f[1]) << 16);
    v.y = (unsigned int)f2bf(f[2]) | ((unsigned int)f2bf(f[3]) << 16);
    v.z = (unsigned int)f2bf(f[4]) | ((unsigned int)f2bf(f[5]) << 16);
    v.w = (unsigned int)f2bf(f[6]) | ((unsigned int)f2bf(f[7]) << 16);
    return v;
}

// ---------- 1. degree + in-edge count (atomics over E) ----------
__global__ void k_count(const int* __restrict__ ei, const float* __restrict__ ew,
                        float* __restrict__ deg, int* __restrict__ cnt) {
    int e = blockIdx.x * 256 + threadIdx.x;
    if (e >= EE) return;
    int d = ei[EE + e];                 // dst row
    atomicAdd(&deg[d], ew[e]);
    atomicAdd(&cnt[d], 1);
}

// ---------- 2. dis = rsqrt(deg + 1) ----------
__global__ void k_dis(float* __restrict__ deg) {
    int i = blockIdx.x * 256 + threadIdx.x;
    if (i >= NN) return;
    float dv = deg[i] + 1.0f;
    deg[i] = rsqrtf(fmaxf(dv, 1e-12f));   // in-place: buffer becomes `dis`
}

// ---------- 3. hierarchical exclusive scan of counts ----------
__global__ void k_scan1(const int* __restrict__ cnt, int* __restrict__ rowoff,
                        int* __restrict__ bsum) {
    __shared__ int wsum[4];
    int i = blockIdx.x * 256 + threadIdx.x;
    int self = (i < NN) ? cnt[i] : 0;
    int lane = threadIdx.x & 63, wid = threadIdx.x >> 6;
    int v = self;
    #pragma unroll
    for (int off = 1; off < 64; off <<= 1) {
        int u = __shfl_up(v, off);
        if (lane >= off) v += u;
    }
    if (lane == 63) wsum[wid] = v;
    __syncthreads();
    int wof = 0;
    for (int k = 0; k < wid; ++k) wof += wsum[k];
    if (i < NN) rowoff[i] = wof + v - self;
    if (threadIdx.x == 255) bsum[blockIdx.x] = wof + v;
}

__global__ void k_scan2(int* __restrict__ bsum) {
    int lane = threadIdx.x;                          // 64 threads
    int base = 0;
    for (int start = 0; start < 80; start += 64) {
        int i = start + lane;
        int self = (i < 80) ? bsum[i] : 0;
        int v = self;
        #pragma unroll
        for (int off = 1; off < 64; off <<= 1) {
            int u = __shfl_up(v, off);
            if (lane >= off) v += u;
        }
        if (i < 80) bsum[i] = base + v - self;
        base += __shfl(v, 63);
    }
}

__global__ void k_scan3(int* __restrict__ rowoff, const int* __restrict__ bsum,
                        int* __restrict__ cur) {
    int i = blockIdx.x * 256 + threadIdx.x;
    if (i < NN) {
        int v = rowoff[i] + bsum[i >> 8];
        rowoff[i] = v; cur[i] = v;
    }
    if (i == NN) rowoff[NN] = EE;
}

// ---------- 4. scatter edges into CSR with precomputed sym-norm weight ----------
__global__ void k_scatter(const int* __restrict__ ei, const float* __restrict__ ew,
                          const float* __restrict__ dis, int* __restrict__ cur,
                          int* __restrict__ csrs, float* __restrict__ csrn) {
    int e = blockIdx.x * 256 + threadIdx.x;
    if (e >= EE) return;
    int s = ei[e], d = ei[EE + e];
    float nrm = dis[s] * ew[e] * dis[d];
    int p = atomicAdd(&cur[d], 1);
    csrs[p] = s; csrn[p] = nrm;
}

// ---------- 5. prop over 128-wide fp32 -> bf16 out: one wave per dst node ----------
__global__ __launch_bounds__(256) void k_prop128(
        const float* __restrict__ t, unsigned short* __restrict__ o,
        const int* __restrict__ rowoff, const int* __restrict__ csrs,
        const float* __restrict__ csrn, const float* __restrict__ dis) {
    int w = (blockIdx.x * 256 + threadIdx.x) >> 6;   // node
    int lane = threadIdx.x & 63;
    if (w >= NN) return;
    float dv = dis[w];
    float sw = dv * dv;                              // self-loop norm
    float a0 = sw * t[(size_t)w * CH + lane];
    float a1 = sw * t[(size_t)w * CH + 64 + lane];
    int e1 = rowoff[w + 1];
    for (int e = rowoff[w]; e < e1; ++e) {
        int   s  = csrs[e];
        float nw = csrn[e];
        a0 += nw * t[(size_t)s * CH + lane];
        a1 += nw * t[(size_t)s * CH + 64 + lane];
    }
    o[(size_t)w * CH + lane]      = f2bf(a0);
    o[(size_t)w * CH + 64 + lane] = f2bf(a1);
}

// ---------- 5b. weight prep: fp32 [4][128][128] (k-major) -> bf16 [4][128][128] n-major ----------
__global__ void k_prepw(const float* __restrict__ W0, const float* __restrict__ W1,
                        const float* __restrict__ W2, const float* __restrict__ W3,
                        unsigned short* __restrict__ T0, unsigned short* __restrict__ T1,
                        unsigned short* __restrict__ T2, unsigned short* __restrict__ T3) {
    const float* W; unsigned short* T;
    switch (blockIdx.z) {
        case 0:  W = W0; T = T0; break;
        case 1:  W = W1; T = T1; break;
        case 2:  W = W2; T = T2; break;
        default: W = W3; T = T3; break;
    }
    int g = blockIdx.y;
    int n = blockIdx.x * 2 + (threadIdx.x >> 7);
    int k = threadIdx.x & 127;
    T[((size_t)g * 128 + n) * 128 + k] = f2bf(W[((size_t)g * 128 + k) * 128 + n]);
}

// ---------- MFMA GEMM shared machinery ----------
// LDS tiles: 128x128 bf16 stored as 16B chunks with XOR swizzle -> conflict-free
// chunk(r, c8) lives at index r*16 + (c8 ^ (r&15)); both A (row-major) and
// B (n-major, i.e. B^T) use the same layout; frag = 8 contiguous bf16 along k.
#define SWZ(r, c8) (((r) << 4) + ((c8) ^ ((r) & 15)))

// ---------- 6. GEMM1: h0 = relu(A[NP,128]bf16 @ W0[g] + b0[g]) -> bf16 [NP,512] ----------
__global__ __launch_bounds__(256) void k_gemm1(
        const unsigned short* __restrict__ A, const unsigned short* __restrict__ Wt,
        const float* __restrict__ bias, unsigned short* __restrict__ out) {
    __shared__ uint4 As[2048];                       // 32 KB
    __shared__ uint4 Bs[2048];                       // 32 KB
    const int    g    = blockIdx.y;
    const size_t row0 = (size_t)blockIdx.x * 128;
    const int    t    = threadIdx.x;

    #pragma unroll
    for (int p = 0; p < 8; ++p) {                    // stage A 128x128 bf16
        int id = t + 256 * p, r = id >> 4, c8 = id & 15;
        As[SWZ(r, c8)] = *(const uint4*)(A + (row0 + r) * CH + c8 * 8);
    }
    const unsigned short* Wg = Wt + (size_t)g * 16384;   // [n][k] bf16
    #pragma unroll
    for (int p = 0; p < 8; ++p) {                    // stage W^T 128x128 bf16
        int id = t + 256 * p, r = id >> 4, c8 = id & 15;
        Bs[SWZ(r, c8)] = *(const uint4*)(Wg + r * CH + c8 * 8);
    }
    __syncthreads();

    const int wid = t >> 6, l = t & 63;
    const int m0 = (wid >> 1) * 64, n0 = (wid & 1) * 64;
    const int lm = l & 15, q = l >> 4;
    f32x4 acc[4][4];
    #pragma unroll
    for (int i = 0; i < 4; ++i)
        #pragma unroll
        for (int j = 0; j < 4; ++j) { acc[i][j][0]=0.f; acc[i][j][1]=0.f; acc[i][j][2]=0.f; acc[i][j][3]=0.f; }

    #pragma unroll
    for (int kc = 0; kc < 4; ++kc) {
        int c8 = kc * 4 + q;
        bf16x8 a[4], b[4];
        #pragma unroll
        for (int i = 0; i < 4; ++i) { int r = m0 + i * 16 + lm; a[i] = *(const bf16x8*)&As[SWZ(r, c8)]; }
        #pragma unroll
        for (int j = 0; j < 4; ++j) { int r = n0 + j * 16 + lm; b[j] = *(const bf16x8*)&Bs[SWZ(r, c8)]; }
        #pragma unroll
        for (int i = 0; i < 4; ++i)
            #pragma unroll
            for (int j = 0; j < 4; ++j)
                acc[i][j] = __builtin_amdgcn_mfma_f32_16x16x32_bf16(a[i], b[j], acc[i][j], 0, 0, 0);
    }

    #pragma unroll
    for (int j = 0; j < 4; ++j) {
        float bb = bias[g * CH + n0 + j * 16 + lm];
        #pragma unroll
        for (int i = 0; i < 4; ++i)
            #pragma unroll
            for (int r = 0; r < 4; ++r) {
                int rowl = m0 + i * 16 + q * 4 + r;   // C/D: row=(lane>>4)*4+reg
                int col  = n0 + j * 16 + lm;          //      col=lane&15
                out[(row0 + rowl) * GC + g * CH + col] = f2bf(fmaxf(acc[i][j][r] + bb, 0.f));
            }
    }
}

// ---------- 7. GEMM2 (fused): S[g] = h0x[g]@Wx1[g] + h0h[g]@Wh1[g] -> bf16 [NP,512] ----------
__global__ __launch_bounds__(256) void k_gemm2(
        const unsigned short* __restrict__ A1, const unsigned short* __restrict__ A2,
        const unsigned short* __restrict__ Wt1, const unsigned short* __restrict__ Wt2,
        unsigned short* __restrict__ outS) {
    __shared__ uint4 As[2048];
    __shared__ uint4 Bs[2048];
    const int    g    = blockIdx.y;
    const size_t row0 = (size_t)blockIdx.x * 128;
    const int    t    = threadIdx.x;
    const int wid = t >> 6, l = t & 63;
    const int m0 = (wid >> 1) * 64, n0 = (wid & 1) * 64;
    const int lm = l & 15, q = l >> 4;
    f32x4 acc[4][4];
    #pragma unroll
    for (int i = 0; i < 4; ++i)
        #pragma unroll
        for (int j = 0; j < 4; ++j) { acc[i][j][0]=0.f; acc[i][j][1]=0.f; acc[i][j][2]=0.f; acc[i][j][3]=0.f; }

    for (int side = 0; side < 2; ++side) {
        if (side) __syncthreads();                   // all waves done reading LDS
        const unsigned short* Ap = side ? A2 : A1;
        const unsigned short* Wg = (side ? Wt2 : Wt1) + (size_t)g * 16384;
        #pragma unroll
        for (int p = 0; p < 8; ++p) {
            int id = t + 256 * p, r = id >> 4, c8 = id & 15;
            As[SWZ(r, c8)] = *(const uint4*)(Ap + (row0 + r) * GC + g * CH + c8 * 8);
        }
        #pragma unroll
        for (int p = 0; p < 8; ++p) {
            int id = t + 256 * p, r = id >> 4, c8 = id & 15;
            Bs[SWZ(r, c8)] = *(const uint4*)(Wg + r * CH + c8 * 8);
        }
        __syncthreads();
        #pragma unroll
        for (int kc = 0; kc < 4; ++kc) {
            int c8 = kc * 4 + q;
            bf16x8 a[4], b[4];
            #pragma unroll
            for (int i = 0; i < 4; ++i) { int r = m0 + i * 16 + lm; a[i] = *(const bf16x8*)&As[SWZ(r, c8)]; }
            #pragma unroll
            for (int j = 0; j < 4; ++j) { int r = n0 + j * 16 + lm; b[j] = *(const bf16x8*)&Bs[SWZ(r, c8)]; }
            #pragma unroll
            for (int i = 0; i < 4; ++i)
                #pragma unroll
                for (int j = 0; j < 4; ++j)
                    acc[i][j] = __builtin_amdgcn_mfma_f32_16x16x32_bf16(a[i], b[j], acc[i][j], 0, 0, 0);
        }
    }

    #pragma unroll
    for (int j = 0; j < 4; ++j)
        #pragma unroll
        for (int i = 0; i < 4; ++i)
            #pragma unroll
            for (int r = 0; r < 4; ++r) {
                int rowl = m0 + i * 16 + q * 4 + r;
                int col  = n0 + j * 16 + lm;
                outS[(row0 + rowl) * GC + g * CH + col] = f2bf(acc[i][j][r]);
            }
}

// ---------- 8. prop over 512-wide bf16: one wave per node, 16B/lane gathers ----------
__global__ __launch_bounds__(256) void k_prop512(
        const unsigned short* __restrict__ Sb, unsigned short* __restrict__ G0,
        const int* __restrict__ rowoff, const int* __restrict__ csrs,
        const float* __restrict__ csrn, const float* __restrict__ dis) {
    int w = (blockIdx.x * 256 + threadIdx.x) >> 6;
    int lane = threadIdx.x & 63;
    if (w >= NN) return;
    const uint4* S4 = (const uint4*)Sb;              // 8 bf16 per lane
    float dv = dis[w], sw = dv * dv;
    float acc[8], vals[8];
    uint4 v = S4[(size_t)w * 64 + lane];
    unpack8(v, vals);
    #pragma unroll
    for (int j = 0; j < 8; ++j) acc[j] = sw * vals[j];
    int e1 = rowoff[w + 1];
    for (int e = rowoff[w]; e < e1; ++e) {
        int   s  = csrs[e];
        float nw = csrn[e];
        v = S4[(size_t)s * 64 + lane];
        unpack8(v, vals);
        #pragma unroll
        for (int j = 0; j < 8; ++j) acc[j] += nw * vals[j];
    }
    ((uint4*)G0)[(size_t)w * 64 + lane] = pack8(acc);
}

// ---------- 9. LSTM gate elementwise ----------
__global__ void k_gates(const unsigned short* __restrict__ G0, const float* __restrict__ c,
                        const float* __restrict__ bx1, const float* __restrict__ bh1,
                        const float* __restrict__ wc, const float* __restrict__ bg,
                        float* __restrict__ out) {
    int idx = blockIdx.x * 256 + threadIdx.x;        // < NHtot (exact grid)
    int n = idx >> 7, hh = idx & 127;
    size_t base = (size_t)n * GC + hh;
    float g0 = bf2f(G0[base])       + bx1[hh]       + bh1[hh];
    float g1 = bf2f(G0[base + 128]) + bx1[128 + hh] + bh1[128 + hh];
    float g2 = bf2f(G0[base + 256]) + bx1[256 + hh] + bh1[256 + hh];
    float g3 = bf2f(G0[base + 384]) + bx1[384 + hh] + bh1[384 + hh];
    float cv = c[idx];
    float I  = 1.f / (1.f + expf(-(g0 + wc[hh]       * cv + bg[hh])));
    float F  = 1.f / (1.f + expf(-(g1 + wc[128 + hh] * cv + bg[128 + hh])));
    float T  = tanhf(g2 + bg[256 + hh]);
    float Cn = F * cv + I * T;
    float O  = 1.f / (1.f + expf(-(g3 + wc[256 + hh] * Cn + bg[384 + hh])));
    out[idx]         = O * tanhf(Cn);                // Hn
    out[NHtot + idx] = Cn;                           // Cn
}

extern "C" void kernel_launch(void* const* d_in, const int* in_sizes, int n_in,
                              void* d_out, int out_size, void* d_ws, size_t ws_size,
                              hipStream_t stream) {
    (void)in_sizes; (void)n_in; (void)out_size; (void)ws_size;
    const float* x   = (const float*)d_in[0];
    const int*   ei  = (const int*)d_in[1];
    const float* ew  = (const float*)d_in[2];
    const float* h   = (const float*)d_in[3];
    const float* c   = (const float*)d_in[4];
    const float* Wx0 = (const float*)d_in[5];
    const float* bx0 = (const float*)d_in[6];
    const float* Wx1 = (const float*)d_in[7];
    const float* bx1 = (const float*)d_in[8];
    const float* Wh0 = (const float*)d_in[9];
    const float* bh0 = (const float*)d_in[10];
    const float* Wh1 = (const float*)d_in[11];
    const float* bh1 = (const float*)d_in[12];
    const float* wc  = (const float*)d_in[13];
    const float* bg  = (const float*)d_in[14];
    float* out = (float*)d_out;

    // Workspace layout (float units). Total ~75.4 MB. All uint4-aligned.
    float* wsf  = (float*)d_ws;
    float* deg  = wsf;                                  // [20480] -> becomes dis
    int*   cnt  = (int*)(wsf + 20480);                  // [20480]
    int*   row  = (int*)(wsf + 40960);                  // [20736]
    int*   cur  = (int*)(wsf + 61696);                  // [20480]
    int*   bsum = (int*)(wsf + 82176);                  // [256]
    int*   csrs = (int*)(wsf + 82432);                  // [E]
    float* csrn = wsf + 402432;                         // [E]
    unsigned short* Wt0x = (unsigned short*)(wsf + 722432);   // [4*128*128] bf16 n-major
    unsigned short* Wt0h = (unsigned short*)(wsf + 755200);
    unsigned short* Wt1x = (unsigned short*)(wsf + 787968);
    unsigned short* Wt1h = (unsigned short*)(wsf + 820736);
    unsigned short* axb  = (unsigned short*)(wsf + 853504);   // [NP*128] bf16
    unsigned short* ahb  = (unsigned short*)(wsf + 2139648);  // [NP*128] bf16
    unsigned short* h0x  = (unsigned short*)(wsf + 3425792);  // [NP*512] bf16
    unsigned short* h0h  = (unsigned short*)(wsf + 8570368);  // [NP*512] bf16
    unsigned short* Sb   = (unsigned short*)(wsf + 13714944); // [NP*512] bf16
    unsigned short* G0   = h0x;                               // alias: h0x dead after GEMM2

    hipMemsetAsync(deg, 0, 2 * 20480 * sizeof(float), stream);  // deg + cnt

    k_count  <<<EE / 256, 256, 0, stream>>>(ei, ew, deg, cnt);
    k_dis    <<<(NN + 255) / 256, 256, 0, stream>>>(deg);
    k_scan1  <<<80, 256, 0, stream>>>(cnt, row, bsum);
    k_scan2  <<<1, 64, 0, stream>>>(bsum);
    k_scan3  <<<80, 256, 0, stream>>>(row, bsum, cur);
    k_scatter<<<EE / 256, 256, 0, stream>>>(ei, ew, deg, cur, csrs, csrn);

    dim3 pw(64, 4, 4);
    k_prepw  <<<pw, 256, 0, stream>>>(Wx0, Wh0, Wx1, Wh1, Wt0x, Wt0h, Wt1x, Wt1h);

    k_prop128<<<NN / 4, 256, 0, stream>>>(x, axb, row, csrs, csrn, deg);
    k_prop128<<<NN / 4, 256, 0, stream>>>(h, ahb, row, csrs, csrn, deg);

    dim3 gg(NP / 128, 4);
    k_gemm1<<<gg, 256, 0, stream>>>(axb, Wt0x, bx0, h0x);
    k_gemm1<<<gg, 256, 0, stream>>>(ahb, Wt0h, bh0, h0h);
    k_gemm2<<<gg, 256, 0, stream>>>(h0x, h0h, Wt1x, Wt1h, Sb);

    k_prop512<<<NN / 4, 256, 0, stream>>>(Sb, G0, row, csrs, csrn, deg);
    k_gates  <<<NHtot / 256, 256, 0, stream>>>(G0, c, bx1, bh1, wc, bg, out);
}

// Round 4
// 287.807 us; speedup vs baseline: 2.1401x; 1.1785x over previous
//
#include <hip/hip_runtime.h>
#include <hip/hip_bf16.h>
#include <stdint.h>

// Problem constants (fixed by the reference)
#define NN    20000      // nodes
#define NP    20096      // nodes padded to 157*128 (garbage rows never read back)
#define EE    320000     // edges (w/o self loops)
#define CH    128        // feature width per gate
#define GC    512        // 4 gates * 128
#define NHtot 2560000    // N*CH

typedef short bf16x8 __attribute__((ext_vector_type(8)));   // 8 bf16 (4 VGPRs)
typedef float f32x4  __attribute__((ext_vector_type(4)));   // 4 fp32 acc

// ---------- bf16 helpers ----------
__device__ __forceinline__ float bf2f(unsigned short u) {
    union { unsigned int i; float f; } c; c.i = ((unsigned int)u) << 16; return c.f;
}
__device__ __forceinline__ unsigned short f2bf(float f) {
    __hip_bfloat16 b = __float2bfloat16(f);           // RNE
    union { __hip_bfloat16 b; unsigned short u; } c; c.b = b; return c.u;
}
__device__ __forceinline__ void unpack8(uint4 v, float* f) {
    f[0] = bf2f((unsigned short)(v.x & 0xffff)); f[1] = bf2f((unsigned short)(v.x >> 16));
    f[2] = bf2f((unsigned short)(v.y & 0xffff)); f[3] = bf2f((unsigned short)(v.y >> 16));
    f[4] = bf2f((unsigned short)(v.z & 0xffff)); f[5] = bf2f((unsigned short)(v.z >> 16));
    f[6] = bf2f((unsigned short)(v.w & 0xffff)); f[7] = bf2f((unsigned short)(v.w >> 16));
}
__device__ __forceinline__ uint4 pack8(const float* f) {
    uint4 v;
    v.x = (unsigned int)f2bf(f[0]) | ((unsigned int)f2bf(f[1]) << 16);
    v.y = (unsigned int)f2bf(f[2]) | ((unsigned int)f2bf(f[3]) << 16);
    v.z = (unsigned int)f2bf(f[4]) | ((unsigned int)f2bf(f[5]) << 16);
    v.w = (unsigned int)f2bf(f[6]) | ((unsigned int)f2bf(f[7]) << 16);
    return v;
}
__device__ __forceinline__ void unpack4(uint2 v, float* f) {
    f[0] = bf2f((unsigned short)(v.x & 0xffff)); f[1] = bf2f((unsigned short)(v.x >> 16));
    f[2] = bf2f((unsigned short)(v.y & 0xffff)); f[3] = bf2f((unsigned short)(v.y >> 16));
}
__device__ __forceinline__ uint2 pack4(const float* f) {
    uint2 v;
    v.x = (unsigned int)f2bf(f[0]) | ((unsigned int)f2bf(f[1]) << 16);
    v.y = (unsigned int)f2bf(f[2]) | ((unsigned int)f2bf(f[3]) << 16);
    return v;
}

// ---------- 1. degree + in-edge count (atomics over E) ----------
__global__ void k_count(const int* __restrict__ ei, const float* __restrict__ ew,
                        float* __restrict__ deg, int* __restrict__ cnt) {
    int e = blockIdx.x * 256 + threadIdx.x;
    if (e >= EE) return;
    int d = ei[EE + e];                 // dst row
    atomicAdd(&deg[d], ew[e]);
    atomicAdd(&cnt[d], 1);
}

// ---------- 2. dis = rsqrt(deg + 1) ----------
__global__ void k_dis(float* __restrict__ deg) {
    int i = blockIdx.x * 256 + threadIdx.x;
    if (i >= NN) return;
    float dv = deg[i] + 1.0f;
    deg[i] = rsqrtf(fmaxf(dv, 1e-12f));   // in-place: buffer becomes `dis`
}

// ---------- 3. hierarchical exclusive scan of counts ----------
__global__ void k_scan1(const int* __restrict__ cnt, int* __restrict__ rowoff,
                        int* __restrict__ bsum) {
    __shared__ int wsum[4];
    int i = blockIdx.x * 256 + threadIdx.x;
    int self = (i < NN) ? cnt[i] : 0;
    int lane = threadIdx.x & 63, wid = threadIdx.x >> 6;
    int v = self;
    #pragma unroll
    for (int off = 1; off < 64; off <<= 1) {
        int u = __shfl_up(v, off);
        if (lane >= off) v += u;
    }
    if (lane == 63) wsum[wid] = v;
    __syncthreads();
    int wof = 0;
    for (int k = 0; k < wid; ++k) wof += wsum[k];
    if (i < NN) rowoff[i] = wof + v - self;
    if (threadIdx.x == 255) bsum[blockIdx.x] = wof + v;
}

__global__ void k_scan2(int* __restrict__ bsum) {
    int lane = threadIdx.x;                          // 64 threads
    int base = 0;
    for (int start = 0; start < 80; start += 64) {
        int i = start + lane;
        int self = (i < 80) ? bsum[i] : 0;
        int v = self;
        #pragma unroll
        for (int off = 1; off < 64; off <<= 1) {
            int u = __shfl_up(v, off);
            if (lane >= off) v += u;
        }
        if (i < 80) bsum[i] = base + v - self;
        base += __shfl(v, 63);
    }
}

__global__ void k_scan3(int* __restrict__ rowoff, const int* __restrict__ bsum,
                        int* __restrict__ cur) {
    int i = blockIdx.x * 256 + threadIdx.x;
    if (i < NN) {
        int v = rowoff[i] + bsum[i >> 8];
        rowoff[i] = v; cur[i] = v;
    }
    if (i == NN) rowoff[NN] = EE;
}

// ---------- 4. scatter edges into CSR with precomputed sym-norm weight ----------
__global__ void k_scatter(const int* __restrict__ ei, const float* __restrict__ ew,
                          const float* __restrict__ dis, int* __restrict__ cur,
                          int* __restrict__ csrs, float* __restrict__ csrn) {
    int e = blockIdx.x * 256 + threadIdx.x;
    if (e >= EE) return;
    int s = ei[e], d = ei[EE + e];
    float nrm = dis[s] * ew[e] * dis[d];
    int p = atomicAdd(&cur[d], 1);
    csrs[p] = s; csrn[p] = nrm;
}

// ---------- 5a. cast & pack x|h into [N][256] bf16 ----------
__global__ void k_castxh(const float* __restrict__ x, const float* __restrict__ h,
                         unsigned short* __restrict__ xhb) {
    int idx = blockIdx.x * 256 + threadIdx.x;        // 0 .. NN*32-1 (exact grid)
    int n = idx >> 5, c4 = idx & 31;
    float4 xv = *(const float4*)(x + (size_t)n * CH + c4 * 4);
    float4 hv = *(const float4*)(h + (size_t)n * CH + c4 * 4);
    float fx[4] = { xv.x, xv.y, xv.z, xv.w };
    float fh[4] = { hv.x, hv.y, hv.z, hv.w };
    *(uint2*)(xhb + (size_t)n * 256 + c4 * 4)       = pack4(fx);
    *(uint2*)(xhb + (size_t)n * 256 + 128 + c4 * 4) = pack4(fh);
}

// ---------- 5b. fused prop over packed 256-wide bf16 rows (x|h together) ----------
// one wave per node, 8B/lane, 2-edge unroll for MLP; 128-thread blocks (2 waves)
__global__ __launch_bounds__(128) void k_prop256(
        const unsigned short* __restrict__ tab, unsigned short* __restrict__ o,
        const int* __restrict__ rowoff, const int* __restrict__ csrs,
        const float* __restrict__ csrn, const float* __restrict__ dis) {
    int w = blockIdx.x * 2 + (threadIdx.x >> 6);     // node (grid exact: NN/2 blocks)
    int lane = threadIdx.x & 63;
    const uint2* T2 = (const uint2*)tab;             // row = 64 uint2 = 512 B
    float dv = dis[w], sw = dv * dv;
    float acc[4], va[4], vb[4];
    uint2 v = T2[(size_t)w * 64 + lane];
    unpack4(v, va);
    #pragma unroll
    for (int j = 0; j < 4; ++j) acc[j] = sw * va[j];
    int e = rowoff[w], e1 = rowoff[w + 1];
    for (; e + 2 <= e1; e += 2) {
        int   s0 = csrs[e],     s1 = csrs[e + 1];
        float n0 = csrn[e],     n1 = csrn[e + 1];
        uint2 v0 = T2[(size_t)s0 * 64 + lane];
        uint2 v1 = T2[(size_t)s1 * 64 + lane];
        unpack4(v0, va); unpack4(v1, vb);
        #pragma unroll
        for (int j = 0; j < 4; ++j) acc[j] += n0 * va[j] + n1 * vb[j];
    }
    if (e < e1) {
        int s = csrs[e]; float nw = csrn[e];
        v = T2[(size_t)s * 64 + lane];
        unpack4(v, va);
        #pragma unroll
        for (int j = 0; j < 4; ++j) acc[j] += nw * va[j];
    }
    ((uint2*)o)[(size_t)w * 64 + lane] = pack4(acc);
}

// ---------- 5c. weight prep: fp32 [4][128][128] k-major -> bf16 n-major ----------
__global__ void k_prepw(const float* __restrict__ W0, const float* __restrict__ W1,
                        const float* __restrict__ W2, const float* __restrict__ W3,
                        unsigned short* __restrict__ T0, unsigned short* __restrict__ T1,
                        unsigned short* __restrict__ T2, unsigned short* __restrict__ T3) {
    const float* W; unsigned short* T;
    switch (blockIdx.z) {
        case 0:  W = W0; T = T0; break;
        case 1:  W = W1; T = T1; break;
        case 2:  W = W2; T = T2; break;
        default: W = W3; T = T3; break;
    }
    int g = blockIdx.y;
    int n = blockIdx.x * 2 + (threadIdx.x >> 7);
    int k = threadIdx.x & 127;
    T[((size_t)g * 128 + n) * 128 + k] = f2bf(W[((size_t)g * 128 + k) * 128 + n]);
}

// ---------- MFMA GEMM shared machinery ----------
#define SWZ(r, c8) (((r) << 4) + ((c8) ^ ((r) & 15)))

// ---------- 6. GEMM1: h0 = relu(A @ W0[g] + b0[g]) -> bf16 [NP,512] ----------
// A = packed prop output [NP][256] bf16; aoff selects x-half (0) or h-half (128)
__global__ __launch_bounds__(256) void k_gemm1(
        const unsigned short* __restrict__ A, int aoff,
        const unsigned short* __restrict__ Wt,
        const float* __restrict__ bias, unsigned short* __restrict__ out) {
    __shared__ uint4 As[2048];                       // 32 KB
    __shared__ uint4 Bs[2048];                       // 32 KB
    const int    g    = blockIdx.y;
    const size_t row0 = (size_t)blockIdx.x * 128;
    const int    t    = threadIdx.x;

    #pragma unroll
    for (int p = 0; p < 8; ++p) {                    // stage A 128x128 bf16
        int id = t + 256 * p, r = id >> 4, c8 = id & 15;
        As[SWZ(r, c8)] = *(const uint4*)(A + (row0 + r) * 256 + aoff + c8 * 8);
    }
    const unsigned short* Wg = Wt + (size_t)g * 16384;   // [n][k] bf16
    #pragma unroll
    for (int p = 0; p < 8; ++p) {                    // stage W^T 128x128 bf16
        int id = t + 256 * p, r = id >> 4, c8 = id & 15;
        Bs[SWZ(r, c8)] = *(const uint4*)(Wg + r * CH + c8 * 8);
    }
    __syncthreads();

    const int wid = t >> 6, l = t & 63;
    const int m0 = (wid >> 1) * 64, n0 = (wid & 1) * 64;
    const int lm = l & 15, q = l >> 4;
    f32x4 acc[4][4];
    #pragma unroll
    for (int i = 0; i < 4; ++i)
        #pragma unroll
        for (int j = 0; j < 4; ++j) { acc[i][j][0]=0.f; acc[i][j][1]=0.f; acc[i][j][2]=0.f; acc[i][j][3]=0.f; }

    #pragma unroll
    for (int kc = 0; kc < 4; ++kc) {
        int c8 = kc * 4 + q;
        bf16x8 a[4], b[4];
        #pragma unroll
        for (int i = 0; i < 4; ++i) { int r = m0 + i * 16 + lm; a[i] = *(const bf16x8*)&As[SWZ(r, c8)]; }
        #pragma unroll
        for (int j = 0; j < 4; ++j) { int r = n0 + j * 16 + lm; b[j] = *(const bf16x8*)&Bs[SWZ(r, c8)]; }
        #pragma unroll
        for (int i = 0; i < 4; ++i)
            #pragma unroll
            for (int j = 0; j < 4; ++j)
                acc[i][j] = __builtin_amdgcn_mfma_f32_16x16x32_bf16(a[i], b[j], acc[i][j], 0, 0, 0);
    }

    #pragma unroll
    for (int j = 0; j < 4; ++j) {
        float bb = bias[g * CH + n0 + j * 16 + lm];
        #pragma unroll
        for (int i = 0; i < 4; ++i)
            #pragma unroll
            for (int r = 0; r < 4; ++r) {
                int rowl = m0 + i * 16 + q * 4 + r;   // C/D: row=(lane>>4)*4+reg
                int col  = n0 + j * 16 + lm;          //      col=lane&15
                out[(row0 + rowl) * GC + g * CH + col] = f2bf(fmaxf(acc[i][j][r] + bb, 0.f));
            }
    }
}

// ---------- 7. GEMM2 (fused): S[g] = h0x[g]@Wx1[g] + h0h[g]@Wh1[g] -> bf16 [NP,512] ----------
__global__ __launch_bounds__(256) void k_gemm2(
        const unsigned short* __restrict__ A1, const unsigned short* __restrict__ A2,
        const unsigned short* __restrict__ Wt1, const unsigned short* __restrict__ Wt2,
        unsigned short* __restrict__ outS) {
    __shared__ uint4 As[2048];
    __shared__ uint4 Bs[2048];
    const int    g    = blockIdx.y;
    const size_t row0 = (size_t)blockIdx.x * 128;
    const int    t    = threadIdx.x;
    const int wid = t >> 6, l = t & 63;
    const int m0 = (wid >> 1) * 64, n0 = (wid & 1) * 64;
    const int lm = l & 15, q = l >> 4;
    f32x4 acc[4][4];
    #pragma unroll
    for (int i = 0; i < 4; ++i)
        #pragma unroll
        for (int j = 0; j < 4; ++j) { acc[i][j][0]=0.f; acc[i][j][1]=0.f; acc[i][j][2]=0.f; acc[i][j][3]=0.f; }

    for (int side = 0; side < 2; ++side) {
        if (side) __syncthreads();                   // all waves done reading LDS
        const unsigned short* Ap = side ? A2 : A1;
        const unsigned short* Wg = (side ? Wt2 : Wt1) + (size_t)g * 16384;
        #pragma unroll
        for (int p = 0; p < 8; ++p) {
            int id = t + 256 * p, r = id >> 4, c8 = id & 15;
            As[SWZ(r, c8)] = *(const uint4*)(Ap + (row0 + r) * GC + g * CH + c8 * 8);
        }
        #pragma unroll
        for (int p = 0; p < 8; ++p) {
            int id = t + 256 * p, r = id >> 4, c8 = id & 15;
            Bs[SWZ(r, c8)] = *(const uint4*)(Wg + r * CH + c8 * 8);
        }
        __syncthreads();
        #pragma unroll
        for (int kc = 0; kc < 4; ++kc) {
            int c8 = kc * 4 + q;
            bf16x8 a[4], b[4];
            #pragma unroll
            for (int i = 0; i < 4; ++i) { int r = m0 + i * 16 + lm; a[i] = *(const bf16x8*)&As[SWZ(r, c8)]; }
            #pragma unroll
            for (int j = 0; j < 4; ++j) { int r = n0 + j * 16 + lm; b[j] = *(const bf16x8*)&Bs[SWZ(r, c8)]; }
            #pragma unroll
            for (int i = 0; i < 4; ++i)
                #pragma unroll
                for (int j = 0; j < 4; ++j)
                    acc[i][j] = __builtin_amdgcn_mfma_f32_16x16x32_bf16(a[i], b[j], acc[i][j], 0, 0, 0);
        }
    }

    #pragma unroll
    for (int j = 0; j < 4; ++j)
        #pragma unroll
        for (int i = 0; i < 4; ++i)
            #pragma unroll
            for (int r = 0; r < 4; ++r) {
                int rowl = m0 + i * 16 + q * 4 + r;
                int col  = n0 + j * 16 + lm;
                outS[(row0 + rowl) * GC + g * CH + col] = f2bf(acc[i][j][r]);
            }
}

// ---------- 8. prop over 512-wide bf16: one wave per node, 16B/lane, 2-edge unroll ----------
__global__ __launch_bounds__(128) void k_prop512(
        const unsigned short* __restrict__ Sb, unsigned short* __restrict__ G0,
        const int* __restrict__ rowoff, const int* __restrict__ csrs,
        const float* __restrict__ csrn, const float* __restrict__ dis) {
    int w = blockIdx.x * 2 + (threadIdx.x >> 6);     // node (grid exact: NN/2 blocks)
    int lane = threadIdx.x & 63;
    const uint4* S4 = (const uint4*)Sb;              // row = 64 uint4 = 1 KB
    float dv = dis[w], sw = dv * dv;
    float acc[8], va[8], vb[8];
    uint4 v = S4[(size_t)w * 64 + lane];
    unpack8(v, va);
    #pragma unroll
    for (int j = 0; j < 8; ++j) acc[j] = sw * va[j];
    int e = rowoff[w], e1 = rowoff[w + 1];
    for (; e + 2 <= e1; e += 2) {
        int   s0 = csrs[e],     s1 = csrs[e + 1];
        float n0 = csrn[e],     n1 = csrn[e + 1];
        uint4 v0 = S4[(size_t)s0 * 64 + lane];
        uint4 v1 = S4[(size_t)s1 * 64 + lane];
        unpack8(v0, va); unpack8(v1, vb);
        #pragma unroll
        for (int j = 0; j < 8; ++j) acc[j] += n0 * va[j] + n1 * vb[j];
    }
    if (e < e1) {
        int s = csrs[e]; float nw = csrn[e];
        v = S4[(size_t)s * 64 + lane];
        unpack8(v, va);
        #pragma unroll
        for (int j = 0; j < 8; ++j) acc[j] += nw * va[j];
    }
    ((uint4*)G0)[(size_t)w * 64 + lane] = pack8(acc);
}

// ---------- 9. LSTM gate elementwise ----------
__global__ void k_gates(const unsigned short* __restrict__ G0, const float* __restrict__ c,
                        const float* __restrict__ bx1, const float* __restrict__ bh1,
                        const float* __restrict__ wc, const float* __restrict__ bg,
                        float* __restrict__ out) {
    int idx = blockIdx.x * 256 + threadIdx.x;        // < NHtot (exact grid)
    int n = idx >> 7, hh = idx & 127;
    size_t base = (size_t)n * GC + hh;
    float g0 = bf2f(G0[base])       + bx1[hh]       + bh1[hh];
    float g1 = bf2f(G0[base + 128]) + bx1[128 + hh] + bh1[128 + hh];
    float g2 = bf2f(G0[base + 256]) + bx1[256 + hh] + bh1[256 + hh];
    float g3 = bf2f(G0[base + 384]) + bx1[384 + hh] + bh1[384 + hh];
    float cv = c[idx];
    float I  = 1.f / (1.f + expf(-(g0 + wc[hh]       * cv + bg[hh])));
    float F  = 1.f / (1.f + expf(-(g1 + wc[128 + hh] * cv + bg[128 + hh])));
    float T  = tanhf(g2 + bg[256 + hh]);
    float Cn = F * cv + I * T;
    float O  = 1.f / (1.f + expf(-(g3 + wc[256 + hh] * Cn + bg[384 + hh])));
    out[idx]         = O * tanhf(Cn);                // Hn
    out[NHtot + idx] = Cn;                           // Cn
}

extern "C" void kernel_launch(void* const* d_in, const int* in_sizes, int n_in,
                              void* d_out, int out_size, void* d_ws, size_t ws_size,
                              hipStream_t stream) {
    (void)in_sizes; (void)n_in; (void)out_size; (void)ws_size;
    const float* x   = (const float*)d_in[0];
    const int*   ei  = (const int*)d_in[1];
    const float* ew  = (const float*)d_in[2];
    const float* h   = (const float*)d_in[3];
    const float* c   = (const float*)d_in[4];
    const float* Wx0 = (const float*)d_in[5];
    const float* bx0 = (const float*)d_in[6];
    const float* Wx1 = (const float*)d_in[7];
    const float* bx1 = (const float*)d_in[8];
    const float* Wh0 = (const float*)d_in[9];
    const float* bh0 = (const float*)d_in[10];
    const float* Wh1 = (const float*)d_in[11];
    const float* bh1 = (const float*)d_in[12];
    const float* wc  = (const float*)d_in[13];
    const float* bg  = (const float*)d_in[14];
    float* out = (float*)d_out;

    // Workspace layout (float units). Total ~85.7 MB. All uint4-aligned.
    float* wsf  = (float*)d_ws;
    float* deg  = wsf;                                  // [20480] -> becomes dis
    int*   cnt  = (int*)(wsf + 20480);                  // [20480]
    int*   row  = (int*)(wsf + 40960);                  // [20736]
    int*   cur  = (int*)(wsf + 61696);                  // [20480]
    int*   bsum = (int*)(wsf + 82176);                  // [256]
    int*   csrs = (int*)(wsf + 82432);                  // [E]
    float* csrn = wsf + 402432;                         // [E]
    unsigned short* Wt0x = (unsigned short*)(wsf + 722432);   // [4*128*128] bf16 n-major
    unsigned short* Wt0h = (unsigned short*)(wsf + 755200);
    unsigned short* Wt1x = (unsigned short*)(wsf + 787968);
    unsigned short* Wt1h = (unsigned short*)(wsf + 820736);
    unsigned short* xhb  = (unsigned short*)(wsf + 853504);   // [NP*256] bf16 packed x|h
    unsigned short* axh  = (unsigned short*)(wsf + 3425792);  // [NP*256] bf16 packed ax|ah
    unsigned short* h0x  = (unsigned short*)(wsf + 5998080);  // [NP*512] bf16
    unsigned short* h0h  = (unsigned short*)(wsf + 11142656); // [NP*512] bf16
    unsigned short* Sb   = (unsigned short*)(wsf + 16287232); // [NP*512] bf16
    unsigned short* G0   = h0x;                               // alias: h0x dead after GEMM2

    hipMemsetAsync(deg, 0, 2 * 20480 * sizeof(float), stream);  // deg + cnt

    k_count  <<<EE / 256, 256, 0, stream>>>(ei, ew, deg, cnt);
    k_dis    <<<(NN + 255) / 256, 256, 0, stream>>>(deg);
    k_scan1  <<<80, 256, 0, stream>>>(cnt, row, bsum);
    k_scan2  <<<1, 64, 0, stream>>>(bsum);
    k_scan3  <<<80, 256, 0, stream>>>(row, bsum, cur);
    k_scatter<<<EE / 256, 256, 0, stream>>>(ei, ew, deg, cur, csrs, csrn);

    dim3 pw(64, 4, 4);
    k_prepw  <<<pw, 256, 0, stream>>>(Wx0, Wh0, Wx1, Wh1, Wt0x, Wt0h, Wt1x, Wt1h);
    k_castxh <<<NN * 32 / 256, 256, 0, stream>>>(x, h, xhb);

    k_prop256<<<NN / 2, 128, 0, stream>>>(xhb, axh, row, csrs, csrn, deg);

    dim3 gg(NP / 128, 4);
    k_gemm1<<<gg, 256, 0, stream>>>(axh, 0,   Wt0x, bx0, h0x);
    k_gemm1<<<gg, 256, 0, stream>>>(axh, 128, Wt0h, bh0, h0h);
    k_gemm2<<<gg, 256, 0, stream>>>(h0x, h0h, Wt1x, Wt1h, Sb);

    k_prop512<<<NN / 2, 128, 0, stream>>>(Sb, G0, row, csrs, csrn, deg);
    k_gates  <<<NHtot / 256, 256, 0, stream>>>(G0, c, bx1, bh1, wc, bg, out);
}